// Round 1
// baseline (278.012 us; speedup 1.0000x reference)
//
#include <hip/hip_runtime.h>

#define TOPK 32

// ---------- helpers ----------
__device__ __forceinline__ unsigned monokey(float f) {
  // order-preserving map float -> uint32 (no NaNs expected)
  unsigned u = __float_as_uint(f);
  return (u & 0x80000000u) ? ~u : (u | 0x80000000u);
}
__device__ __forceinline__ float inv_monokey(unsigned k) {
  return __uint_as_float((k & 0x80000000u) ? (k ^ 0x80000000u) : ~k);
}

// ---------- kernel A: scores GEMM ----------
// scores[row][c] = dot(x[row][0:512],   keys1[c])        for c in [0,512)
//                = dot(x[row][512:1024],keys2[c-512])    for c in [512,1024)
// M=R rows, N=1024, K=512. fp32 vector GEMM, 64x64 tile, BK=32, 256 thr, 4x4/thread.
__global__ __launch_bounds__(256) void score_gemm(
    const float* __restrict__ x,
    const float* __restrict__ keys1,
    const float* __restrict__ keys2,
    float* __restrict__ scores) {
  __shared__ __align__(16) float As[32][68];  // [k][m], row stride 68 floats = 272B (16B-aligned)
  __shared__ __align__(16) float Bs[32][68];  // [k][n]

  const int row0 = blockIdx.x * 64;
  const int col0 = blockIdx.y * 64;

  const float* Kp;
  int xoff, kb;
  if (col0 < 512) { Kp = keys1; xoff = 0;   kb = col0; }
  else            { Kp = keys2; xoff = 512; kb = col0 - 512; }

  const int tid = threadIdx.x;
  const int tx = tid & 15, ty = tid >> 4;   // 16x16 thread grid, 4x4 outputs each
  const int lm = tid >> 3;                  // 0..31 (tile row for loads)
  const int lk = (tid & 7) * 4;             // 0..28 (k offset for float4 load)

  float acc[4][4] = {};

  for (int k0 = 0; k0 < 512; k0 += 32) {
#pragma unroll
    for (int h = 0; h < 2; ++h) {
      const int m = lm + h * 32;
      float4 av = *(const float4*)&x[(size_t)(row0 + m) * 1024 + xoff + k0 + lk];
      As[lk + 0][m] = av.x; As[lk + 1][m] = av.y;
      As[lk + 2][m] = av.z; As[lk + 3][m] = av.w;
      float4 bv = *(const float4*)&Kp[(size_t)(kb + m) * 512 + k0 + lk];
      Bs[lk + 0][m] = bv.x; Bs[lk + 1][m] = bv.y;
      Bs[lk + 2][m] = bv.z; Bs[lk + 3][m] = bv.w;
    }
    __syncthreads();
#pragma unroll
    for (int kk = 0; kk < 32; ++kk) {
      float4 a4 = *(const float4*)&As[kk][ty * 4];
      float4 b4 = *(const float4*)&Bs[kk][tx * 4];
      float av[4] = {a4.x, a4.y, a4.z, a4.w};
      float bv[4] = {b4.x, b4.y, b4.z, b4.w};
#pragma unroll
      for (int i = 0; i < 4; ++i)
#pragma unroll
        for (int j = 0; j < 4; ++j)
          acc[i][j] = fmaf(av[i], bv[j], acc[i][j]);
    }
    __syncthreads();
  }

#pragma unroll
  for (int i = 0; i < 4; ++i) {
    float4 o = {acc[i][0], acc[i][1], acc[i][2], acc[i][3]};
    *(float4*)&scores[(size_t)(row0 + ty * 4 + i) * 1024 + col0 + tx * 4] = o;
  }
}

// ---------- kernel B: per-row topk + combine + softmax + gather ----------
// One 64-lane wave per row.
__global__ __launch_bounds__(64) void topk_gather(
    const float* __restrict__ scores,  // [R][1024]
    const float* __restrict__ values,  // [262144][512]
    float* __restrict__ y) {           // [R][512]
  const int row = blockIdx.x;
  const int lane = threadIdx.x;
  const float* srow = scores + (size_t)row * 1024;

  // lane-local slices: slot j<4 -> idx 4*lane+j ; slot j>=4 -> 256+4*lane+(j-4)
  float v1[8], v2[8];
  {
    float4 a = *(const float4*)&srow[4 * lane];
    float4 b = *(const float4*)&srow[256 + 4 * lane];
    v1[0] = a.x; v1[1] = a.y; v1[2] = a.z; v1[3] = a.w;
    v1[4] = b.x; v1[5] = b.y; v1[6] = b.z; v1[7] = b.w;
    float4 c = *(const float4*)&srow[512 + 4 * lane];
    float4 d = *(const float4*)&srow[768 + 4 * lane];
    v2[0] = c.x; v2[1] = c.y; v2[2] = c.z; v2[3] = c.w;
    v2[4] = d.x; v2[5] = d.y; v2[6] = d.z; v2[7] = d.w;
  }

  __shared__ float s1v[TOPK], s2v[TOPK], topv[TOPK], wts[TOPK];
  __shared__ int s1i[TOPK], s2i[TOPK], topl[TOPK], vidx[TOPK];

  // ---- top-32 of scores1 ----
  for (int t = 0; t < TOPK; ++t) {
    float bv = v1[0]; int bs = 0;
#pragma unroll
    for (int j = 1; j < 8; ++j)
      if (v1[j] > bv) { bv = v1[j]; bs = j; }
    int gidx = (bs < 4) ? 4 * lane + bs : 256 + 4 * lane + (bs - 4);
    unsigned long long pk =
        ((unsigned long long)monokey(bv) << 32) | (unsigned)(0xFFFFFFFFu - (unsigned)gidx);
#pragma unroll
    for (int off = 32; off; off >>= 1) {
      unsigned long long o = __shfl_xor(pk, off);
      if (o > pk) pk = o;
    }
    int widx = (int)(0xFFFFFFFFu - (unsigned)(pk & 0xFFFFFFFFu));
    if (lane == 0) { s1v[t] = inv_monokey((unsigned)(pk >> 32)); s1i[t] = widx; }
    int olane = (widx < 256) ? (widx >> 2) : ((widx - 256) >> 2);
    int oslot = (widx < 256) ? (widx & 3) : 4 + ((widx - 256) & 3);
    if (lane == olane) v1[oslot] = -__builtin_inff();
  }

  // ---- top-32 of scores2 ----
  for (int t = 0; t < TOPK; ++t) {
    float bv = v2[0]; int bs = 0;
#pragma unroll
    for (int j = 1; j < 8; ++j)
      if (v2[j] > bv) { bv = v2[j]; bs = j; }
    int gidx = (bs < 4) ? 4 * lane + bs : 256 + 4 * lane + (bs - 4);
    unsigned long long pk =
        ((unsigned long long)monokey(bv) << 32) | (unsigned)(0xFFFFFFFFu - (unsigned)gidx);
#pragma unroll
    for (int off = 32; off; off >>= 1) {
      unsigned long long o = __shfl_xor(pk, off);
      if (o > pk) pk = o;
    }
    int widx = (int)(0xFFFFFFFFu - (unsigned)(pk & 0xFFFFFFFFu));
    if (lane == 0) { s2v[t] = inv_monokey((unsigned)(pk >> 32)); s2i[t] = widx; }
    int olane = (widx < 256) ? (widx >> 2) : ((widx - 256) >> 2);
    int oslot = (widx < 256) ? (widx & 3) : 4 + ((widx - 256) & 3);
    if (lane == olane) v2[oslot] = -__builtin_inff();
  }
  __syncthreads();

  // ---- 32x32 products; lane owns lin = 16*lane .. 16*lane+15, lin = rank1*32+rank2 ----
  const int r1 = lane >> 1;
  const int j0 = (lane & 1) * 16;
  const float a1 = s1v[r1];
  float p[16];
#pragma unroll
  for (int j = 0; j < 16; ++j) p[j] = a1 * s2v[j0 + j];

  for (int t = 0; t < TOPK; ++t) {
    float bv = p[0]; int bs = 0;
#pragma unroll
    for (int j = 1; j < 16; ++j)
      if (p[j] > bv) { bv = p[j]; bs = j; }
    int lin = 16 * lane + bs;
    unsigned long long pk =
        ((unsigned long long)monokey(bv) << 32) | (unsigned)(1023u - (unsigned)lin);
#pragma unroll
    for (int off = 32; off; off >>= 1) {
      unsigned long long o = __shfl_xor(pk, off);
      if (o > pk) pk = o;
    }
    int wlin = (int)(1023u - (unsigned)(pk & 0xFFFFFFFFu));
    if (lane == 0) { topv[t] = inv_monokey((unsigned)(pk >> 32)); topl[t] = wlin; }
    if (lane == (wlin >> 4)) p[wlin & 15] = -__builtin_inff();
  }
  __syncthreads();

  // ---- softmax weights + value indices ----
  {
    float m = topv[0];  // first selected is the max
    float e = (lane < TOPK) ? __expf(topv[lane] - m) : 0.0f;
    float s = e;
#pragma unroll
    for (int off = 32; off; off >>= 1) s += __shfl_xor(s, off);
    if (lane < TOPK) {
      wts[lane] = e / s;
      int lin = topl[lane];
      vidx[lane] = s1i[lin >> 5] * 512 + s2i[lin & 31];
    }
  }
  __syncthreads();

  // ---- gather + weighted sum: y[row][c] = sum_k w[k] * values[vidx[k]][c] ----
  float4 acc0 = {0, 0, 0, 0}, acc1 = {0, 0, 0, 0};
  for (int t = 0; t < TOPK; ++t) {
    float w = wts[t];
    const float* vr = values + (size_t)vidx[t] * 512;
    float4 va = *(const float4*)&vr[4 * lane];
    float4 vb = *(const float4*)&vr[256 + 4 * lane];
    acc0.x = fmaf(w, va.x, acc0.x); acc0.y = fmaf(w, va.y, acc0.y);
    acc0.z = fmaf(w, va.z, acc0.z); acc0.w = fmaf(w, va.w, acc0.w);
    acc1.x = fmaf(w, vb.x, acc1.x); acc1.y = fmaf(w, vb.y, acc1.y);
    acc1.z = fmaf(w, vb.z, acc1.z); acc1.w = fmaf(w, vb.w, acc1.w);
  }
  float* yr = y + (size_t)row * 512;
  *(float4*)&yr[4 * lane] = acc0;
  *(float4*)&yr[256 + 4 * lane] = acc1;
}

extern "C" void kernel_launch(void* const* d_in, const int* in_sizes, int n_in,
                              void* d_out, int out_size, void* d_ws, size_t ws_size,
                              hipStream_t stream) {
  const float* x      = (const float*)d_in[0];  // [R][1024]
  const float* values = (const float*)d_in[1];  // [262144][512]
  const float* keys1  = (const float*)d_in[2];  // [512][512]
  const float* keys2  = (const float*)d_in[3];  // [512][512]
  float* y = (float*)d_out;

  const int R = in_sizes[0] / 1024;  // 8192 rows
  float* scores = (float*)d_ws;      // R*1024 floats = 33.5 MB

  dim3 gridA(R / 64, 16);
  score_gemm<<<gridA, 256, 0, stream>>>(x, keys1, keys2, scores);
  topk_gather<<<R, 64, 0, stream>>>(scores, values, y);
}

// Round 2
// 274.487 us; speedup vs baseline: 1.0128x; 1.0128x over previous
//
#include <hip/hip_runtime.h>

#define TOPK 32

// ---------- helpers ----------
__device__ __forceinline__ unsigned monokey(float f) {
  unsigned u = __float_as_uint(f);
  return (u & 0x80000000u) ? ~u : (u | 0x80000000u);
}
__device__ __forceinline__ float inv_monokey(unsigned k) {
  return __uint_as_float((k & 0x80000000u) ? (k ^ 0x80000000u) : ~k);
}

// XOR-swizzled LDS float offset for tiles stored [row][32 k-floats] as float4
// groups. Group g of row r lives at group g ^ ((r>>3)&7).  Row stride 32 floats
// = 128B (bank-period) would be a 16-way conflict unswizzled; the XOR spreads
// the 16 distinct B-read addresses across all 32 banks (2-way = free, m136).
__device__ __forceinline__ int lds_off(int r, int g) {
  return r * 32 + ((g ^ ((r >> 3) & 7)) << 2);
}

// ---------- kernel A: scores GEMM ----------
// scores[row][c] = dot(x[row][0:512],   keys1[c])      c in [0,512)
//                = dot(x[row][512:],    keys2[c-512])  c in [512,1024)
// 128x128 tile, BK=32, 256 threads, 8x8 acc/thread. fp32 vector FMA.
__global__ __launch_bounds__(256) void score_gemm(
    const float* __restrict__ x,
    const float* __restrict__ keys1,
    const float* __restrict__ keys2,
    float* __restrict__ scores) {
  __shared__ __align__(16) float As[128 * 32];
  __shared__ __align__(16) float Bs[128 * 32];

  const int row0 = blockIdx.x * 128;
  const int col0 = blockIdx.y * 128;

  const float* Kp;
  int xoff, kb;
  if (col0 < 512) { Kp = keys1; xoff = 0;   kb = col0; }
  else            { Kp = keys2; xoff = 512; kb = col0 - 512; }

  const int tid = threadIdx.x;
  const int g = tid & 7;        // k-group for loads (4 floats each)
  const int rb = tid >> 3;      // 0..31 base row for loads
  const int tx = tid & 15, ty = tid >> 4;
  const int m0 = ty * 8, n0 = tx * 8;

  float acc[8][8] = {};

  for (int k0 = 0; k0 < 512; k0 += 32) {
#pragma unroll
    for (int h = 0; h < 4; ++h) {
      const int r = rb + h * 32;
      float4 av = *(const float4*)&x[(size_t)(row0 + r) * 1024 + xoff + k0 + g * 4];
      *(float4*)&As[lds_off(r, g)] = av;
      float4 bv = *(const float4*)&Kp[(size_t)(kb + r) * 512 + k0 + g * 4];
      *(float4*)&Bs[lds_off(r, g)] = bv;
    }
    __syncthreads();

#pragma unroll
    for (int G = 0; G < 8; ++G) {
      float4 a[8], b[8];
#pragma unroll
      for (int i = 0; i < 8; ++i) a[i] = *(const float4*)&As[lds_off(m0 + i, G)];
#pragma unroll
      for (int j = 0; j < 8; ++j) b[j] = *(const float4*)&Bs[lds_off(n0 + j, G)];
#pragma unroll
      for (int i = 0; i < 8; ++i)
#pragma unroll
        for (int j = 0; j < 8; ++j) {
          acc[i][j] = fmaf(a[i].x, b[j].x, acc[i][j]);
          acc[i][j] = fmaf(a[i].y, b[j].y, acc[i][j]);
          acc[i][j] = fmaf(a[i].z, b[j].z, acc[i][j]);
          acc[i][j] = fmaf(a[i].w, b[j].w, acc[i][j]);
        }
    }
    __syncthreads();
  }

#pragma unroll
  for (int i = 0; i < 8; ++i) {
    float4 o0 = {acc[i][0], acc[i][1], acc[i][2], acc[i][3]};
    float4 o1 = {acc[i][4], acc[i][5], acc[i][6], acc[i][7]};
    float* dst = &scores[(size_t)(row0 + m0 + i) * 1024 + col0 + n0];
    *(float4*)&dst[0] = o0;
    *(float4*)&dst[4] = o1;
  }
}

// ---------- kernel B: per-row topk + combine + softmax + gather ----------
// One 64-lane wave per row.
__global__ __launch_bounds__(64) void topk_gather(
    const float* __restrict__ scores,  // [R][1024]
    const float* __restrict__ values,  // [262144][512]
    float* __restrict__ y) {           // [R][512]
  const int row = blockIdx.x;
  const int lane = threadIdx.x;
  const float* srow = scores + (size_t)row * 1024;

  float v1[8], v2[8];
  {
    float4 a = *(const float4*)&srow[4 * lane];
    float4 b = *(const float4*)&srow[256 + 4 * lane];
    v1[0] = a.x; v1[1] = a.y; v1[2] = a.z; v1[3] = a.w;
    v1[4] = b.x; v1[5] = b.y; v1[6] = b.z; v1[7] = b.w;
    float4 c = *(const float4*)&srow[512 + 4 * lane];
    float4 d = *(const float4*)&srow[768 + 4 * lane];
    v2[0] = c.x; v2[1] = c.y; v2[2] = c.z; v2[3] = c.w;
    v2[4] = d.x; v2[5] = d.y; v2[6] = d.z; v2[7] = d.w;
  }

  __shared__ float s1v[TOPK], s2v[TOPK], topv[TOPK], wts[TOPK];
  __shared__ int s1i[TOPK], s2i[TOPK], topl[TOPK], vidx[TOPK];

  // ---- top-32 of scores1 ----
  for (int t = 0; t < TOPK; ++t) {
    float bv = v1[0]; int bs = 0;
#pragma unroll
    for (int j = 1; j < 8; ++j)
      if (v1[j] > bv) { bv = v1[j]; bs = j; }
    int gidx = (bs < 4) ? 4 * lane + bs : 256 + 4 * lane + (bs - 4);
    unsigned long long pk =
        ((unsigned long long)monokey(bv) << 32) | (unsigned)(0xFFFFFFFFu - (unsigned)gidx);
#pragma unroll
    for (int off = 32; off; off >>= 1) {
      unsigned long long o = __shfl_xor(pk, off);
      if (o > pk) pk = o;
    }
    int widx = (int)(0xFFFFFFFFu - (unsigned)(pk & 0xFFFFFFFFu));
    if (lane == 0) { s1v[t] = inv_monokey((unsigned)(pk >> 32)); s1i[t] = widx; }
    int olane = (widx < 256) ? (widx >> 2) : ((widx - 256) >> 2);
    int oslot = (widx < 256) ? (widx & 3) : 4 + ((widx - 256) & 3);
    if (lane == olane) v1[oslot] = -__builtin_inff();
  }

  // ---- top-32 of scores2 ----
  for (int t = 0; t < TOPK; ++t) {
    float bv = v2[0]; int bs = 0;
#pragma unroll
    for (int j = 1; j < 8; ++j)
      if (v2[j] > bv) { bv = v2[j]; bs = j; }
    int gidx = (bs < 4) ? 4 * lane + bs : 256 + 4 * lane + (bs - 4);
    unsigned long long pk =
        ((unsigned long long)monokey(bv) << 32) | (unsigned)(0xFFFFFFFFu - (unsigned)gidx);
#pragma unroll
    for (int off = 32; off; off >>= 1) {
      unsigned long long o = __shfl_xor(pk, off);
      if (o > pk) pk = o;
    }
    int widx = (int)(0xFFFFFFFFu - (unsigned)(pk & 0xFFFFFFFFu));
    if (lane == 0) { s2v[t] = inv_monokey((unsigned)(pk >> 32)); s2i[t] = widx; }
    int olane = (widx < 256) ? (widx >> 2) : ((widx - 256) >> 2);
    int oslot = (widx < 256) ? (widx & 3) : 4 + ((widx - 256) & 3);
    if (lane == olane) v2[oslot] = -__builtin_inff();
  }
  __syncthreads();

  // ---- 32x32 products; lane owns lin = 16*lane .. +15; lin = rank1*32+rank2 ----
  const int r1 = lane >> 1;
  const int j0 = (lane & 1) * 16;
  const float a1 = s1v[r1];
  float p[16];
#pragma unroll
  for (int j = 0; j < 16; ++j) p[j] = a1 * s2v[j0 + j];

  for (int t = 0; t < TOPK; ++t) {
    float bv = p[0]; int bs = 0;
#pragma unroll
    for (int j = 1; j < 16; ++j)
      if (p[j] > bv) { bv = p[j]; bs = j; }
    int lin = 16 * lane + bs;
    unsigned long long pk =
        ((unsigned long long)monokey(bv) << 32) | (unsigned)(1023u - (unsigned)lin);
#pragma unroll
    for (int off = 32; off; off >>= 1) {
      unsigned long long o = __shfl_xor(pk, off);
      if (o > pk) pk = o;
    }
    int wlin = (int)(1023u - (unsigned)(pk & 0xFFFFFFFFu));
    if (lane == 0) { topv[t] = inv_monokey((unsigned)(pk >> 32)); topl[t] = wlin; }
    if (lane == (wlin >> 4)) p[wlin & 15] = -__builtin_inff();
  }
  __syncthreads();

  // ---- softmax weights + value indices ----
  {
    float m = topv[0];
    float e = (lane < TOPK) ? __expf(topv[lane] - m) : 0.0f;
    float s = e;
#pragma unroll
    for (int off = 32; off; off >>= 1) s += __shfl_xor(s, off);
    if (lane < TOPK) {
      wts[lane] = e / s;
      int lin = topl[lane];
      vidx[lane] = s1i[lin >> 5] * 512 + s2i[lin & 31];
    }
  }
  __syncthreads();

  // ---- gather + weighted sum ----
  float4 acc0 = {0, 0, 0, 0}, acc1 = {0, 0, 0, 0};
  for (int t = 0; t < TOPK; ++t) {
    float w = wts[t];
    const float* vr = values + (size_t)vidx[t] * 512;
    float4 va = *(const float4*)&vr[4 * lane];
    float4 vb = *(const float4*)&vr[256 + 4 * lane];
    acc0.x = fmaf(w, va.x, acc0.x); acc0.y = fmaf(w, va.y, acc0.y);
    acc0.z = fmaf(w, va.z, acc0.z); acc0.w = fmaf(w, va.w, acc0.w);
    acc1.x = fmaf(w, vb.x, acc1.x); acc1.y = fmaf(w, vb.y, acc1.y);
    acc1.z = fmaf(w, vb.z, acc1.z); acc1.w = fmaf(w, vb.w, acc1.w);
  }
  float* yr = y + (size_t)row * 512;
  *(float4*)&yr[4 * lane] = acc0;
  *(float4*)&yr[256 + 4 * lane] = acc1;
}

extern "C" void kernel_launch(void* const* d_in, const int* in_sizes, int n_in,
                              void* d_out, int out_size, void* d_ws, size_t ws_size,
                              hipStream_t stream) {
  const float* x      = (const float*)d_in[0];  // [R][1024]
  const float* values = (const float*)d_in[1];  // [262144][512]
  const float* keys1  = (const float*)d_in[2];  // [512][512]
  const float* keys2  = (const float*)d_in[3];  // [512][512]
  float* y = (float*)d_out;

  const int R = in_sizes[0] / 1024;  // 8192 rows
  float* scores = (float*)d_ws;      // R*1024 floats = 33.5 MB

  dim3 gridA(R / 128, 8);
  score_gemm<<<gridA, 256, 0, stream>>>(x, keys1, keys2, scores);
  topk_gather<<<R, 64, 0, stream>>>(scores, values, y);
}

// Round 3
// 215.122 us; speedup vs baseline: 1.2923x; 1.2760x over previous
//
#include <hip/hip_runtime.h>

#define TOPK 32

// ---------- helpers ----------
__device__ __forceinline__ unsigned monokey(float f) {
  // order-preserving, invertible map float -> uint32 (no NaNs expected)
  unsigned u = __float_as_uint(f);
  return (u & 0x80000000u) ? ~u : (u | 0x80000000u);
}
__device__ __forceinline__ float inv_monokey(unsigned k) {
  return __uint_as_float((k & 0x80000000u) ? (k ^ 0x80000000u) : ~k);
}
__device__ __forceinline__ void lgkm_fence() {
  asm volatile("s_waitcnt lgkmcnt(0)" ::: "memory");
}

// Find T = 32nd-largest key among the wave's N*64 keys (N per lane), via
// bitwise binary search. Each round is N v_cmp->ballot + scalar popcounts:
// no DS ops, no shuffles. Early-exit when the count hits exactly TOPK.
template <int N>
__device__ __forceinline__ unsigned radix_thresh(const unsigned* k) {
  unsigned prefix = 0;
  for (int b = 31; b >= 0; --b) {
    unsigned cand = prefix | (1u << b);
    int c = 0;
#pragma unroll
    for (int j = 0; j < N; ++j)
      c += __popcll(__ballot(k[j] >= cand));
    if (c >= TOPK) {
      prefix = cand;
      if (c == TOPK) break;  // set {k >= prefix} is exactly the top-32
    }
  }
  return prefix;
}

// XOR-swizzled LDS float offset for [row][32 k-floats] tiles in float4 groups.
__device__ __forceinline__ int lds_off(int r, int g) {
  return r * 32 + ((g ^ ((r >> 3) & 7)) << 2);
}

// ---------- kernel A: scores GEMM ----------
// scores[row][c] = dot(x[row][0:512],   keys1[c])      c in [0,512)
//                = dot(x[row][512:],    keys2[c-512])  c in [512,1024)
// 128x128 tile, BK=32, 256 threads, 8x8 acc/thread. fp32 vector FMA.
__global__ __launch_bounds__(256) void score_gemm(
    const float* __restrict__ x,
    const float* __restrict__ keys1,
    const float* __restrict__ keys2,
    float* __restrict__ scores) {
  __shared__ __align__(16) float As[128 * 32];
  __shared__ __align__(16) float Bs[128 * 32];

  const int row0 = blockIdx.x * 128;
  const int col0 = blockIdx.y * 128;

  const float* Kp;
  int xoff, kb;
  if (col0 < 512) { Kp = keys1; xoff = 0;   kb = col0; }
  else            { Kp = keys2; xoff = 512; kb = col0 - 512; }

  const int tid = threadIdx.x;
  const int g = tid & 7;
  const int rb = tid >> 3;
  const int tx = tid & 15, ty = tid >> 4;
  const int m0 = ty * 8, n0 = tx * 8;

  float acc[8][8] = {};

  for (int k0 = 0; k0 < 512; k0 += 32) {
#pragma unroll
    for (int h = 0; h < 4; ++h) {
      const int r = rb + h * 32;
      float4 av = *(const float4*)&x[(size_t)(row0 + r) * 1024 + xoff + k0 + g * 4];
      *(float4*)&As[lds_off(r, g)] = av;
      float4 bv = *(const float4*)&Kp[(size_t)(kb + r) * 512 + k0 + g * 4];
      *(float4*)&Bs[lds_off(r, g)] = bv;
    }
    __syncthreads();

#pragma unroll
    for (int G = 0; G < 8; ++G) {
      float4 a[8], b[8];
#pragma unroll
      for (int i = 0; i < 8; ++i) a[i] = *(const float4*)&As[lds_off(m0 + i, G)];
#pragma unroll
      for (int j = 0; j < 8; ++j) b[j] = *(const float4*)&Bs[lds_off(n0 + j, G)];
#pragma unroll
      for (int i = 0; i < 8; ++i)
#pragma unroll
        for (int j = 0; j < 8; ++j) {
          acc[i][j] = fmaf(a[i].x, b[j].x, acc[i][j]);
          acc[i][j] = fmaf(a[i].y, b[j].y, acc[i][j]);
          acc[i][j] = fmaf(a[i].z, b[j].z, acc[i][j]);
          acc[i][j] = fmaf(a[i].w, b[j].w, acc[i][j]);
        }
    }
    __syncthreads();
  }

#pragma unroll
  for (int i = 0; i < 8; ++i) {
    float4 o0 = {acc[i][0], acc[i][1], acc[i][2], acc[i][3]};
    float4 o1 = {acc[i][4], acc[i][5], acc[i][6], acc[i][7]};
    float* dst = &scores[(size_t)(row0 + m0 + i) * 1024 + col0 + n0];
    *(float4*)&dst[0] = o0;
    *(float4*)&dst[4] = o1;
  }
}

// ---------- kernel B: per-row topk + combine + softmax + gather ----------
// 256 threads = 4 waves; each wave owns one row independently (no block sync).
__global__ __launch_bounds__(256) void topk_gather(
    const float* __restrict__ scores,  // [R][1024]
    const float* __restrict__ values,  // [262144][512]
    float* __restrict__ y) {           // [R][512]
  const int wid = threadIdx.x >> 6;
  const int lane = threadIdx.x & 63;
  const int row = blockIdx.x * 4 + wid;
  const float* srow = scores + (size_t)row * 1024;

  // keys only (monokey is invertible) to keep VGPR low
  unsigned k1[8], k2[8];
  {
    float4 a = *(const float4*)&srow[4 * lane];
    float4 b = *(const float4*)&srow[256 + 4 * lane];
    k1[0] = monokey(a.x); k1[1] = monokey(a.y); k1[2] = monokey(a.z); k1[3] = monokey(a.w);
    k1[4] = monokey(b.x); k1[5] = monokey(b.y); k1[6] = monokey(b.z); k1[7] = monokey(b.w);
    float4 c = *(const float4*)&srow[512 + 4 * lane];
    float4 d = *(const float4*)&srow[768 + 4 * lane];
    k2[0] = monokey(c.x); k2[1] = monokey(c.y); k2[2] = monokey(c.z); k2[3] = monokey(c.w);
    k2[4] = monokey(d.x); k2[5] = monokey(d.y); k2[6] = monokey(d.z); k2[7] = monokey(d.w);
  }

  __shared__ float s1v[4][TOPK], s2v[4][TOPK], tvv[4][TOPK], wts[4][TOPK];
  __shared__ int s1i[4][TOPK], s2i[4][TOPK], vidx[4][TOPK];

  const unsigned long long mlt = (1ull << lane) - 1;  // lanes below me

  // ---- top-32 of half 1 ----
  {
    unsigned T = radix_thresh<8>(k1);
    int base = 0;
#pragma unroll
    for (int j = 0; j < 8; ++j) {
      bool take = (k1[j] >= T);
      unsigned long long m = __ballot(take);
      int pos = base + __popcll(m & mlt);
      if (take && pos < TOPK) {
        s1v[wid][pos] = inv_monokey(k1[j]);
        s1i[wid][pos] = (j < 4) ? 4 * lane + j : 256 + 4 * lane + (j - 4);
      }
      base += __popcll(m);
    }
  }
  // ---- top-32 of half 2 ----
  {
    unsigned T = radix_thresh<8>(k2);
    int base = 0;
#pragma unroll
    for (int j = 0; j < 8; ++j) {
      bool take = (k2[j] >= T);
      unsigned long long m = __ballot(take);
      int pos = base + __popcll(m & mlt);
      if (take && pos < TOPK) {
        s2v[wid][pos] = inv_monokey(k2[j]);
        s2i[wid][pos] = (j < 4) ? 4 * lane + j : 256 + 4 * lane + (j - 4);
      }
      base += __popcll(m);
    }
  }
  lgkm_fence();

  // ---- 32x32 products: lane covers slots (r1, j0..j0+15); lin = 16*lane+j ----
  {
    const int r1 = lane >> 1;
    const int j0 = (lane & 1) * 16;
    const float a1 = s1v[wid][r1];
    unsigned kp[16];
#pragma unroll
    for (int j = 0; j < 16; ++j) kp[j] = monokey(a1 * s2v[wid][j0 + j]);

    unsigned T = radix_thresh<16>(kp);
    int base = 0;
#pragma unroll
    for (int j = 0; j < 16; ++j) {
      bool take = (kp[j] >= T);
      unsigned long long m = __ballot(take);
      int pos = base + __popcll(m & mlt);
      if (take && pos < TOPK) {
        int lin = 16 * lane + j;
        tvv[wid][pos] = inv_monokey(kp[j]);
        vidx[wid][pos] = s1i[wid][lin >> 5] * 512 + s2i[wid][lin & 31];
      }
      base += __popcll(m);
    }
  }
  lgkm_fence();

  // ---- softmax over the 32 selected products ----
  {
    float v = (lane < TOPK) ? tvv[wid][lane] : -__builtin_inff();
    float mx = v;
#pragma unroll
    for (int off = 32; off; off >>= 1) mx = fmaxf(mx, __shfl_xor(mx, off));
    float e = (lane < TOPK) ? __expf(v - mx) : 0.0f;
    float s = e;
#pragma unroll
    for (int off = 32; off; off >>= 1) s += __shfl_xor(s, off);
    if (lane < TOPK) wts[wid][lane] = e / s;
  }
  lgkm_fence();

  // ---- gather + weighted sum: y[row][c] = sum_t w[t] * values[vidx[t]][c] ----
  float4 acc0 = {0, 0, 0, 0}, acc1 = {0, 0, 0, 0};
  for (int t = 0; t < TOPK; ++t) {
    float w = wts[wid][t];
    const float* vr = values + (size_t)vidx[wid][t] * 512;
    float4 va = *(const float4*)&vr[4 * lane];
    float4 vb = *(const float4*)&vr[256 + 4 * lane];
    acc0.x = fmaf(w, va.x, acc0.x); acc0.y = fmaf(w, va.y, acc0.y);
    acc0.z = fmaf(w, va.z, acc0.z); acc0.w = fmaf(w, va.w, acc0.w);
    acc1.x = fmaf(w, vb.x, acc1.x); acc1.y = fmaf(w, vb.y, acc1.y);
    acc1.z = fmaf(w, vb.z, acc1.z); acc1.w = fmaf(w, vb.w, acc1.w);
  }
  float* yr = y + (size_t)row * 512;
  *(float4*)&yr[4 * lane] = acc0;
  *(float4*)&yr[256 + 4 * lane] = acc1;
}

extern "C" void kernel_launch(void* const* d_in, const int* in_sizes, int n_in,
                              void* d_out, int out_size, void* d_ws, size_t ws_size,
                              hipStream_t stream) {
  const float* x      = (const float*)d_in[0];  // [R][1024]
  const float* values = (const float*)d_in[1];  // [262144][512]
  const float* keys1  = (const float*)d_in[2];  // [512][512]
  const float* keys2  = (const float*)d_in[3];  // [512][512]
  float* y = (float*)d_out;

  const int R = in_sizes[0] / 1024;  // 8192 rows
  float* scores = (float*)d_ws;      // R*1024 floats = 33.5 MB

  dim3 gridA(R / 128, 8);
  score_gemm<<<gridA, 256, 0, stream>>>(x, keys1, keys2, scores);
  topk_gather<<<R / 4, 256, 0, stream>>>(scores, values, y);
}